// Round 11
// baseline (234.008 us; speedup 1.0000x reference)
//
#include <hip/hip_runtime.h>
#include <hip/hip_fp16.h>
#include <math.h>

#define EPSF 1e-7f

#define K3GRID  512        // scatter blocks (bucket dimension)
#define K3BLK   1024       // 512*16 waves = 8192 = 100% of wave slots
#define K4BLK   1024
#define MAXBINS 512        // static LDS counter bound in scatter

// fast path: 2048-node partitions, 8B records {meta, half2(g,b)}, cap 44 (even!)
// bucket layout: BIN-MAJOR  bkt[bin][block][cap]  -> gather reads contiguous 176KB
#define PB_NEW  11
#define PSZ_NEW (1 << PB_NEW)
#define CAPF    44
#define HALFCAP (CAPF / 2)

struct Scalars { double mse_num, mse_den, pv_sum, pv_cnt, phys_sum; };

typedef float f2v __attribute__((ext_vector_type(2)));
typedef float f4v __attribute__((ext_vector_type(4)));
typedef int   i2v __attribute__((ext_vector_type(2)));
typedef unsigned u2v __attribute__((ext_vector_type(2)));
typedef unsigned u4v __attribute__((ext_vector_type(4)));

__device__ __forceinline__ float4 nt_ld_f4(const float4* p) {
    f4v v = __builtin_nontemporal_load((const f4v*)p);
    return make_float4(v.x, v.y, v.z, v.w);
}
__device__ __forceinline__ int2 nt_ld_i2(const int2* p) {
    i2v v = __builtin_nontemporal_load((const i2v*)p);
    return make_int2(v.x, v.y);
}
__device__ __forceinline__ uint4 nt_ld_u4(const uint4* p) {
    u4v v = __builtin_nontemporal_load((const u4v*)p);
    return make_uint4(v.x, v.y, v.z, v.w);
}
__device__ __forceinline__ int nt_ld_i(const int* p) {
    return __builtin_nontemporal_load(p);
}
__device__ __forceinline__ float nt_ld_f(const float* p) {
    return __builtin_nontemporal_load(p);
}

__global__ void zero_scalars_kernel(double* s) {
    int i = threadIdx.x;
    if (i < 5) s[i] = 0.0;
}

__global__ void zero_f32_kernel(float* p, int n) {
    int stride = gridDim.x * blockDim.x;
    for (int i = blockIdx.x * blockDim.x + threadIdx.x; i < n; i += stride)
        p[i] = 0.0f;
}

// Block-wide sum reduction (valid on thread 0). blockDim.x <= 1024, mult of 64.
__device__ double blockReduceSum(double v) {
    __shared__ double red[16];
    #pragma unroll
    for (int off = 32; off > 0; off >>= 1)
        v += __shfl_down(v, off, 64);
    int lane = threadIdx.x & 63;
    int wid  = threadIdx.x >> 6;
    __syncthreads();
    if (lane == 0) red[wid] = v;
    __syncthreads();
    if (threadIdx.x == 0) {
        double s = 0.0;
        int nw = blockDim.x >> 6;
        for (int w = 0; w < nw; ++w) s += red[w];
        v = s;
    }
    return v;
}

__device__ __forceinline__ void msg_compute(float2 ps, float2 po, float2 at,
                                            float es0, float es1, float em0, float em1,
                                            float& P, float& Q)
{
    float g  = at.x * es0 + em0;
    float bb = at.y * es1 + em1;
    float t1 = ps.x * po.x + ps.y * po.y;
    float t2 = ps.y * po.x - ps.x * po.y;
    float vs = ps.x * ps.x + ps.y * ps.y;
    P =  g  * (vs - t1) - bb * t2;
    Q = -bb * (vs - t1) - g  * t2;
}

// Pass 1 (fallback path only)
__global__ void pass1_nodes(const float2* __restrict__ pred,
                            const float4* __restrict__ ty,
                            const float4* __restrict__ mask,
                            const int*    __restrict__ bus,
                            const float*  __restrict__ tvm,
                            const float*  __restrict__ xymean,
                            const float*  __restrict__ xystd,
                            float2*       __restrict__ calc,
                            Scalars* sc, int n, int seed_calc)
{
    float xs0 = xystd[0] + EPSF, xs1 = xystd[1] + EPSF;
    float xs2 = xystd[2] + EPSF, xs3 = xystd[3] + EPSF;
    float xm0 = xymean[0], xm1 = xymean[1], xm2 = xymean[2], xm3 = xymean[3];

    double mse_num = 0.0, mse_den = 0.0, pv_sum = 0.0, pv_cnt = 0.0;
    int stride = gridDim.x * blockDim.x;
    for (int i = blockIdx.x * blockDim.x + threadIdx.x; i < n; i += stride) {
        float2 p = pred[i];
        float4 t = nt_ld_f4(&ty[i]);
        float4 m = nt_ld_f4(&mask[i]);
        float d0 = p.x - t.z, d1 = p.y - t.w;
        mse_num += (double)(d0 * d0 * m.z + d1 * d1 * m.w);
        mse_den += (double)(m.z + m.w);
        calc[i] = seed_calc ? make_float2(t.x * xs0 + xm0, t.y * xs1 + xm1)
                            : make_float2(0.0f, 0.0f);
        float er0 = p.x * xs2 + xm2;
        float er1 = p.y * xs3 + xm3;
        float vmsq = er0 * er0 + er1 * er1;
        if (nt_ld_i(&bus[i]) == 1) {
            float tv = nt_ld_f(&tvm[i]);
            pv_sum += (double)fabsf(vmsq - tv * tv);
            pv_cnt += 1.0;
        }
    }
    mse_num = blockReduceSum(mse_num);
    mse_den = blockReduceSum(mse_den);
    pv_sum  = blockReduceSum(pv_sum);
    pv_cnt  = blockReduceSum(pv_cnt);
    if (threadIdx.x == 0) {
        atomicAdd(&sc->mse_num, mse_num);
        atomicAdd(&sc->mse_den, mse_den);
        atomicAdd(&sc->pv_sum,  pv_sum);
        atomicAdd(&sc->pv_cnt,  pv_cnt);
    }
}

// ---------------- fast path: 8B records {meta, half2(g,b)}, bin-major ----------------
// meta = lid<<20 | other. n <= 2^20. Overflow path stays exact fp32.
// bkt slot address: ((bin * K3GRID + block) * CAPF + rank)

__global__ __launch_bounds__(K3BLK)
void scatter_h2(const int*    __restrict__ ei,    // (2, E)
                const float2* __restrict__ ea,
                const float2* __restrict__ pred,
                const float*  __restrict__ emean,
                const float*  __restrict__ estd,
                uint2*        __restrict__ bkt,
                unsigned int* __restrict__ gcnt,   // [nbins][K3GRID]
                float*        __restrict__ calc,   // overflow accumulator
                int nE, int nbins)
{
    __shared__ unsigned int lcnt[MAXBINS];
    for (int i = threadIdx.x; i < nbins; i += blockDim.x) lcnt[i] = 0;
    __syncthreads();

    float es0 = estd[0] + EPSF, es1 = estd[1] + EPSF;
    float em0 = emean[0], em1 = emean[1];

    int tid = blockIdx.x * blockDim.x + threadIdx.x;
    int stride = gridDim.x * blockDim.x;
    int npair = nE >> 1;

    for (int q = tid; q < npair; q += stride) {
        int2 av = nt_ld_i2(&((const int2*)ei)[q]);
        int2 bv = nt_ld_i2(&((const int2*)(ei + nE))[q]);
        float4 e2 = nt_ld_f4(&((const float4*)ea)[q]);
        float g0 = e2.x * es0 + em0, b0 = e2.y * es1 + em1;
        float g1 = e2.z * es0 + em0, b1 = e2.w * es1 + em1;
        unsigned h0 = __builtin_bit_cast(unsigned, __floats2half2_rn(g0, b0));
        unsigned h1 = __builtin_bit_cast(unsigned, __floats2half2_rn(g1, b1));

        int self[4]  = { av.x, bv.x, av.y, bv.y };
        int other[4] = { bv.x, av.x, bv.y, av.y };
        unsigned hgb[4] = { h0, h0, h1, h1 };
        float gg[4]  = { g0, g0, g1, g1 };
        float bbv[4] = { b0, b0, b1, b1 };

        // phase 1: 4 independent rank atomics
        int bin[4]; unsigned r[4];
        #pragma unroll
        for (int u = 0; u < 4; ++u) {
            bin[u] = self[u] >> PB_NEW;
            r[u] = atomicAdd(&lcnt[bin[u]], 1u);
        }
        // phase 2: 4 independent stores (or rare exact-fp32 overflow)
        #pragma unroll
        for (int u = 0; u < 4; ++u) {
            if (r[u] < (unsigned)CAPF) {
                uint2 rec;
                rec.x = ((unsigned)(self[u] & (PSZ_NEW - 1)) << 20) |
                        (unsigned)other[u];
                rec.y = hgb[u];
                bkt[((size_t)bin[u] * K3GRID + blockIdx.x) * CAPF + r[u]] = rec;
            } else {
                float2 ps = pred[self[u]];
                float2 po = pred[other[u]];
                float t1 = ps.x * po.x + ps.y * po.y;
                float t2 = ps.y * po.x - ps.x * po.y;
                float vs = ps.x * ps.x + ps.y * ps.y;
                float P =  gg[u]  * (vs - t1) - bbv[u] * t2;
                float Q = -bbv[u] * (vs - t1) - gg[u]  * t2;
                unsafeAtomicAdd(&calc[2 * (size_t)self[u]],     P);
                unsafeAtomicAdd(&calc[2 * (size_t)self[u] + 1], Q);
            }
        }
    }
    if ((nE & 1) && tid == 0) {
        int k = nE - 1;
        int a = ei[k], b = ei[nE + k];
        float2 at = ea[k];
        float g = at.x * es0 + em0, bb = at.y * es1 + em1;
        unsigned h = __builtin_bit_cast(unsigned, __floats2half2_rn(g, bb));
        int self[2] = { a, b }, other[2] = { b, a };
        #pragma unroll
        for (int u = 0; u < 2; ++u) {
            int bin = self[u] >> PB_NEW;
            unsigned r = atomicAdd(&lcnt[bin], 1u);
            if (r < (unsigned)CAPF) {
                uint2 rec;
                rec.x = ((unsigned)(self[u] & (PSZ_NEW - 1)) << 20) |
                        (unsigned)other[u];
                rec.y = h;
                bkt[((size_t)bin * K3GRID + blockIdx.x) * CAPF + r] = rec;
            } else {
                float2 ps = pred[self[u]];
                float2 po = pred[other[u]];
                float P, Q;
                msg_compute(ps, po, at, es0, es1, em0, em1, P, Q);
                unsafeAtomicAdd(&calc[2 * (size_t)self[u]],     P);
                unsafeAtomicAdd(&calc[2 * (size_t)self[u] + 1], Q);
            }
        }
    }

    __syncthreads();
    for (int i = threadIdx.x; i < nbins; i += blockDim.x)
        gcnt[(size_t)i * K3GRID + blockIdx.x] = min(lcnt[i], (unsigned)CAPF);
}

// Fused gather: block p reads ONE contiguous 176KB bucket region (bin-major),
// paired uint4 loads; pred[o] fp32 direct; + MSE/PV/phys epilogue.
__global__ __launch_bounds__(K4BLK)
void gather_fused(const uint2*        __restrict__ bkt,
                  const unsigned int* __restrict__ gcnt,
                  const float2* __restrict__ pred,
                  const float*  __restrict__ calc,   // overflow
                  const float4* __restrict__ ty,
                  const float4* __restrict__ mask,
                  const int*    __restrict__ bus,
                  const float*  __restrict__ tvm,
                  const float*  __restrict__ xymean,
                  const float*  __restrict__ xystd,
                  Scalars* sc, int n, int nbins)
{
    __shared__ float accx[PSZ_NEW];
    __shared__ float accy[PSZ_NEW];
    __shared__ float2 plds[PSZ_NEW];
    __shared__ unsigned int cnts[K3GRID];

    int p = blockIdx.x;
    int base = p << PB_NEW;
    for (int i = threadIdx.x; i < PSZ_NEW; i += blockDim.x) {
        accx[i] = 0.0f; accy[i] = 0.0f;
        int g = base + i;
        plds[i] = (g < n) ? pred[g] : make_float2(0.0f, 0.0f);
    }
    // contiguous counter load (bin-major gcnt)
    for (int b = threadIdx.x; b < K3GRID; b += blockDim.x)
        cnts[b] = gcnt[(size_t)p * K3GRID + b];
    __syncthreads();

    // pair loop over this partition's CONTIGUOUS bucket region:
    // pair index f -> bucket b = f / HALFCAP, slot t = 2*(f mod HALFCAP)
    const int pairs = K3GRID * HALFCAP;
    const uint4* reg4 = (const uint4*)(bkt + (size_t)p * K3GRID * CAPF);
    for (int f = threadIdx.x; f < pairs; f += K4BLK) {
        int b  = f / HALFCAP;           // compile-time -> strength-reduced
        int t  = (f - b * HALFCAP) * 2;
        unsigned c = cnts[b];
        if ((unsigned)t < c) {
            uint4 rr = nt_ld_u4(&reg4[f]);
            bool v1 = (unsigned)(t + 1) < c;
            int o0   = (int)(rr.x & 0xFFFFFu);
            int lid0 = (int)(rr.x >> 20);
            float2 po0 = pred[o0];
            int lid1 = 0;
            float2 po1 = make_float2(0.0f, 0.0f);
            if (v1) {
                int o1 = (int)(rr.z & 0xFFFFFu);
                lid1 = (int)(rr.z >> 20);
                po1  = pred[o1];
            }
            {
                __half2 h2 = __builtin_bit_cast(__half2, rr.y);
                float g  = __low2float(h2);
                float bb = __high2float(h2);
                float2 ps = plds[lid0];
                float t1 = ps.x * po0.x + ps.y * po0.y;
                float t2 = ps.y * po0.x - ps.x * po0.y;
                float vs = ps.x * ps.x + ps.y * ps.y;
                float P =  g  * (vs - t1) - bb * t2;
                float Q = -bb * (vs - t1) - g  * t2;
                atomicAdd(&accx[lid0], P);
                atomicAdd(&accy[lid0], Q);
            }
            if (v1) {
                __half2 h2 = __builtin_bit_cast(__half2, rr.w);
                float g  = __low2float(h2);
                float bb = __high2float(h2);
                float2 ps = plds[lid1];
                float t1 = ps.x * po1.x + ps.y * po1.y;
                float t2 = ps.y * po1.x - ps.x * po1.y;
                float vs = ps.x * ps.x + ps.y * ps.y;
                float P =  g  * (vs - t1) - bb * t2;
                float Q = -bb * (vs - t1) - g  * t2;
                atomicAdd(&accx[lid1], P);
                atomicAdd(&accy[lid1], Q);
            }
        }
    }
    __syncthreads();

    // epilogue: MSE + PV + phys for this partition's nodes
    float xs0 = xystd[0] + EPSF, xs1 = xystd[1] + EPSF;
    float xs2 = xystd[2] + EPSF, xs3 = xystd[3] + EPSF;
    float xm0 = xymean[0], xm1 = xymean[1], xm2 = xymean[2], xm3 = xymean[3];

    double mse_num = 0.0, mse_den = 0.0, pv_sum = 0.0, pv_cnt = 0.0, phys = 0.0;
    for (int i = threadIdx.x; i < PSZ_NEW; i += blockDim.x) {
        int g = base + i;
        if (g < n) {
            float2 pp = plds[i];
            float4 t = nt_ld_f4(&ty[g]);
            float4 m = nt_ld_f4(&mask[g]);
            float d0 = pp.x - t.z, d1 = pp.y - t.w;
            mse_num += (double)(d0 * d0 * m.z + d1 * d1 * m.w);
            mse_den += (double)(m.z + m.w);
            float er0 = pp.x * xs2 + xm2;
            float er1 = pp.y * xs3 + xm3;
            float vmsq = er0 * er0 + er1 * er1;
            if (nt_ld_i(&bus[g]) == 1) {
                float tv = nt_ld_f(&tvm[g]);
                pv_sum += (double)fabsf(vmsq - tv * tv);
                pv_cnt += 1.0;
            }
            float2 ov = ((const float2*)calc)[g];
            float vx = t.x * xs0 + xm0 + accx[i] + ov.x;
            float vy = t.y * xs1 + xm1 + accy[i] + ov.y;
            phys += (double)vx * (double)vx + (double)vy * (double)vy;
        }
    }
    mse_num = blockReduceSum(mse_num);
    mse_den = blockReduceSum(mse_den);
    pv_sum  = blockReduceSum(pv_sum);
    pv_cnt  = blockReduceSum(pv_cnt);
    phys    = blockReduceSum(phys);
    if (threadIdx.x == 0) {
        atomicAdd(&sc->mse_num, mse_num);
        atomicAdd(&sc->mse_den, mse_den);
        atomicAdd(&sc->pv_sum,  pv_sum);
        atomicAdd(&sc->pv_cnt,  pv_cnt);
        atomicAdd(&sc->phys_sum, phys);
    }
}

// ---------------- fallback path: direct atomics (exact) ----------------

__global__ void pass2_edges(const int*    __restrict__ ei,
                            const float2* __restrict__ ea,
                            const float2* __restrict__ pred,
                            const float*  __restrict__ emean,
                            const float*  __restrict__ estd,
                            float*        __restrict__ calc,
                            int nE)
{
    float es0 = estd[0] + EPSF, es1 = estd[1] + EPSF;
    float em0 = emean[0], em1 = emean[1];
    int stride = gridDim.x * blockDim.x;
    for (int k = blockIdx.x * blockDim.x + threadIdx.x; k < nE; k += stride) {
        int a = ei[k];
        int b = ei[nE + k];
        float2 at = ea[k];
        float2 pa = pred[a];
        float2 pb = pred[b];
        float Pa, Qa, Pb, Qb;
        msg_compute(pa, pb, at, es0, es1, em0, em1, Pa, Qa);
        msg_compute(pb, pa, at, es0, es1, em0, em1, Pb, Qb);
        unsafeAtomicAdd(&calc[2 * (size_t)a],     Pa);
        unsafeAtomicAdd(&calc[2 * (size_t)a + 1], Qa);
        unsafeAtomicAdd(&calc[2 * (size_t)b],     Pb);
        unsafeAtomicAdd(&calc[2 * (size_t)b + 1], Qb);
    }
}

__global__ void pass3_phys(const float2* __restrict__ calc, Scalars* sc, int n)
{
    double s = 0.0;
    int stride = gridDim.x * blockDim.x;
    for (int i = blockIdx.x * blockDim.x + threadIdx.x; i < n; i += stride) {
        float2 c = calc[i];
        s += (double)c.x * (double)c.x + (double)c.y * (double)c.y;
    }
    s = blockReduceSum(s);
    if (threadIdx.x == 0) atomicAdd(&sc->phys_sum, s);
}

__global__ void finalize_kernel(const Scalars* __restrict__ sc, float* __restrict__ out, int n)
{
    if (threadIdx.x == 0 && blockIdx.x == 0) {
        double mse  = sc->mse_num / (sc->mse_den + 1e-6);
        double phys = sc->phys_sum / (2.0 * (double)n);
        double pv   = (sc->pv_cnt > 0.0) ? (sc->pv_sum / fmax(sc->pv_cnt, 1.0)) : 0.0;
        double total = 0.8 * mse + 0.2 * phys + 0.1 * pv;
        out[0] = (float)total;
        out[1] = (float)mse;
        out[2] = (float)phys;
        out[3] = (float)pv;
    }
}

extern "C" void kernel_launch(void* const* d_in, const int* in_sizes, int n_in,
                              void* d_out, int out_size, void* d_ws, size_t ws_size,
                              hipStream_t stream) {
    const float2* pred   = (const float2*)d_in[0];
    const float4* ty     = (const float4*)d_in[1];
    const float4* mask   = (const float4*)d_in[2];
    const int*    ei     = (const int*)d_in[3];
    const float2* ea     = (const float2*)d_in[4];
    const int*    bus    = (const int*)d_in[5];
    const float*  tvm    = (const float*)d_in[6];
    const float*  xymean = (const float*)d_in[7];
    const float*  xystd  = (const float*)d_in[8];
    const float*  emean  = (const float*)d_in[9];
    const float*  estd   = (const float*)d_in[10];
    float* out = (float*)d_out;

    int n  = in_sizes[0] / 2;   // nodes
    int nE = in_sizes[3] / 2;   // edges

    char* basep = (char*)d_ws;
    Scalars* sc = (Scalars*)basep;
    size_t head = 64;
    float* calc = (float*)(basep + head);
    head += (size_t)2 * n * sizeof(float);
    head = (head + 15) & ~(size_t)15;

    const int BLK = 256, GRID = 2048;

    // ---- fast tier: PB=11, 8B records, cap=CAPF, bin-major buckets ----
    int nbinsN = (n + PSZ_NEW - 1) >> PB_NEW;
    size_t slotsN = (size_t)K3GRID * nbinsN;
    size_t offN = head + slotsN * sizeof(unsigned int);
    offN = (offN + 15) & ~(size_t)15;
    size_t needN = offN + slotsN * (size_t)CAPF * sizeof(uint2);
    bool useNew = (n <= (1 << 20)) && (nbinsN <= MAXBINS) && (needN <= ws_size);

    zero_scalars_kernel<<<1, 64, 0, stream>>>((double*)sc);

    if (useNew) {
        unsigned int* gcnt = (unsigned int*)(basep + head);
        uint2* bkt = (uint2*)(basep + offN);

        zero_f32_kernel<<<1024, 256, 0, stream>>>(calc, 2 * n);  // overflow accumulator
        scatter_h2<<<K3GRID, K3BLK, 0, stream>>>(ei, ea, pred, emean, estd,
                                                 bkt, gcnt, calc, nE, nbinsN);
        gather_fused<<<nbinsN, K4BLK, 0, stream>>>(bkt, gcnt, pred, calc, ty, mask,
                                                   bus, tvm, xymean, xystd, sc, n, nbinsN);
        finalize_kernel<<<1, 64, 0, stream>>>(sc, out, n);
        return;
    }

    // ---- fallback: direct atomics (exact) ----
    pass1_nodes<<<GRID, BLK, 0, stream>>>(pred, ty, mask, bus, tvm, xymean, xystd,
                                          (float2*)calc, sc, n, /*seed=*/1);
    pass2_edges<<<GRID, BLK, 0, stream>>>(ei, ea, pred, emean, estd, calc, nE);
    pass3_phys<<<GRID, BLK, 0, stream>>>((const float2*)calc, sc, n);
    finalize_kernel<<<1, 64, 0, stream>>>(sc, out, n);
}

// Round 12
// 221.808 us; speedup vs baseline: 1.0550x; 1.0550x over previous
//
#include <hip/hip_runtime.h>
#include <hip/hip_fp16.h>
#include <math.h>

#define EPSF 1e-7f

#define K3GRID  512        // scatter blocks (bucket dimension)
#define K3BLK   1024       // 512*16 waves = 8192 = 100% of wave slots
#define K4BLK   1024
#define MAXBINS 512        // static LDS counter bound in scatter

// fast path: 2048-node partitions, 8B records {meta, half2(g,b)}, cap 44 (even)
// bucket layout: BLOCK-MAJOR  bkt[block][bin][cap]  (best measured, R10)
#define PB_NEW  11
#define PSZ_NEW (1 << PB_NEW)
#define CAPF    44
#define HALFCAP (CAPF / 2)

struct Scalars { double mse_num, mse_den, pv_sum, pv_cnt, phys_sum; };

typedef float f2v __attribute__((ext_vector_type(2)));
typedef float f4v __attribute__((ext_vector_type(4)));
typedef int   i2v __attribute__((ext_vector_type(2)));
typedef unsigned u4v __attribute__((ext_vector_type(4)));

__device__ __forceinline__ float4 nt_ld_f4(const float4* p) {
    f4v v = __builtin_nontemporal_load((const f4v*)p);
    return make_float4(v.x, v.y, v.z, v.w);
}
__device__ __forceinline__ int2 nt_ld_i2(const int2* p) {
    i2v v = __builtin_nontemporal_load((const i2v*)p);
    return make_int2(v.x, v.y);
}
__device__ __forceinline__ uint4 nt_ld_u4(const uint4* p) {
    u4v v = __builtin_nontemporal_load((const u4v*)p);
    return make_uint4(v.x, v.y, v.z, v.w);
}
__device__ __forceinline__ int nt_ld_i(const int* p) {
    return __builtin_nontemporal_load(p);
}
__device__ __forceinline__ float nt_ld_f(const float* p) {
    return __builtin_nontemporal_load(p);
}

// zero the overflow accumulator AND the 5 scalar accumulators (one dispatch)
__global__ void zero_ws_kernel(float* __restrict__ calc, double* __restrict__ s, int n2) {
    if (blockIdx.x == 0 && threadIdx.x < 5) s[threadIdx.x] = 0.0;
    int stride = gridDim.x * blockDim.x;
    for (int i = blockIdx.x * blockDim.x + threadIdx.x; i < n2; i += stride)
        calc[i] = 0.0f;
}

// Block-wide sum reduction (valid on thread 0). blockDim.x <= 1024, mult of 64.
__device__ double blockReduceSum(double v) {
    __shared__ double red[16];
    #pragma unroll
    for (int off = 32; off > 0; off >>= 1)
        v += __shfl_down(v, off, 64);
    int lane = threadIdx.x & 63;
    int wid  = threadIdx.x >> 6;
    __syncthreads();
    if (lane == 0) red[wid] = v;
    __syncthreads();
    if (threadIdx.x == 0) {
        double s = 0.0;
        int nw = blockDim.x >> 6;
        for (int w = 0; w < nw; ++w) s += red[w];
        v = s;
    }
    return v;
}

__device__ __forceinline__ void msg_compute(float2 ps, float2 po, float2 at,
                                            float es0, float es1, float em0, float em1,
                                            float& P, float& Q)
{
    float g  = at.x * es0 + em0;
    float bb = at.y * es1 + em1;
    float t1 = ps.x * po.x + ps.y * po.y;
    float t2 = ps.y * po.x - ps.x * po.y;
    float vs = ps.x * ps.x + ps.y * ps.y;
    P =  g  * (vs - t1) - bb * t2;
    Q = -bb * (vs - t1) - g  * t2;
}

// Pass 1 (fallback path only)
__global__ void pass1_nodes(const float2* __restrict__ pred,
                            const float4* __restrict__ ty,
                            const float4* __restrict__ mask,
                            const int*    __restrict__ bus,
                            const float*  __restrict__ tvm,
                            const float*  __restrict__ xymean,
                            const float*  __restrict__ xystd,
                            float2*       __restrict__ calc,
                            Scalars* sc, int n, int seed_calc)
{
    float xs0 = xystd[0] + EPSF, xs1 = xystd[1] + EPSF;
    float xs2 = xystd[2] + EPSF, xs3 = xystd[3] + EPSF;
    float xm0 = xymean[0], xm1 = xymean[1], xm2 = xymean[2], xm3 = xymean[3];

    double mse_num = 0.0, mse_den = 0.0, pv_sum = 0.0, pv_cnt = 0.0;
    int stride = gridDim.x * blockDim.x;
    for (int i = blockIdx.x * blockDim.x + threadIdx.x; i < n; i += stride) {
        float2 p = pred[i];
        float4 t = nt_ld_f4(&ty[i]);
        float4 m = nt_ld_f4(&mask[i]);
        float d0 = p.x - t.z, d1 = p.y - t.w;
        mse_num += (double)(d0 * d0 * m.z + d1 * d1 * m.w);
        mse_den += (double)(m.z + m.w);
        calc[i] = seed_calc ? make_float2(t.x * xs0 + xm0, t.y * xs1 + xm1)
                            : make_float2(0.0f, 0.0f);
        float er0 = p.x * xs2 + xm2;
        float er1 = p.y * xs3 + xm3;
        float vmsq = er0 * er0 + er1 * er1;
        if (nt_ld_i(&bus[i]) == 1) {
            float tv = nt_ld_f(&tvm[i]);
            pv_sum += (double)fabsf(vmsq - tv * tv);
            pv_cnt += 1.0;
        }
    }
    mse_num = blockReduceSum(mse_num);
    mse_den = blockReduceSum(mse_den);
    pv_sum  = blockReduceSum(pv_sum);
    pv_cnt  = blockReduceSum(pv_cnt);
    if (threadIdx.x == 0) {
        atomicAdd(&sc->mse_num, mse_num);
        atomicAdd(&sc->mse_den, mse_den);
        atomicAdd(&sc->pv_sum,  pv_sum);
        atomicAdd(&sc->pv_cnt,  pv_cnt);
    }
}

// ---------------- fast path: 8B records {meta, half2(g,b)}, block-major ----------------
// meta = lid<<20 | other. n <= 2^20. Overflow path stays exact fp32.

__global__ __launch_bounds__(K3BLK)
void scatter_h2(const int*    __restrict__ ei,    // (2, E)
                const float2* __restrict__ ea,
                const float2* __restrict__ pred,
                const float*  __restrict__ emean,
                const float*  __restrict__ estd,
                uint2*        __restrict__ bkt,
                unsigned int* __restrict__ gcnt,   // [K3GRID][nbins]
                float*        __restrict__ calc,   // overflow accumulator
                int nE, int nbins)
{
    __shared__ unsigned int lcnt[MAXBINS];
    for (int i = threadIdx.x; i < nbins; i += blockDim.x) lcnt[i] = 0;
    __syncthreads();

    float es0 = estd[0] + EPSF, es1 = estd[1] + EPSF;
    float em0 = emean[0], em1 = emean[1];

    int tid = blockIdx.x * blockDim.x + threadIdx.x;
    int stride = gridDim.x * blockDim.x;
    int npair = nE >> 1;

    for (int q = tid; q < npair; q += stride) {
        int2 av = nt_ld_i2(&((const int2*)ei)[q]);
        int2 bv = nt_ld_i2(&((const int2*)(ei + nE))[q]);
        float4 e2 = nt_ld_f4(&((const float4*)ea)[q]);
        float g0 = e2.x * es0 + em0, b0 = e2.y * es1 + em1;
        float g1 = e2.z * es0 + em0, b1 = e2.w * es1 + em1;
        unsigned h0 = __builtin_bit_cast(unsigned, __floats2half2_rn(g0, b0));
        unsigned h1 = __builtin_bit_cast(unsigned, __floats2half2_rn(g1, b1));

        int self[4]  = { av.x, bv.x, av.y, bv.y };
        int other[4] = { bv.x, av.x, bv.y, av.y };
        unsigned hgb[4] = { h0, h0, h1, h1 };
        float gg[4]  = { g0, g0, g1, g1 };
        float bbv[4] = { b0, b0, b1, b1 };

        // phase 1: 4 independent rank atomics
        int bin[4]; unsigned r[4];
        #pragma unroll
        for (int u = 0; u < 4; ++u) {
            bin[u] = self[u] >> PB_NEW;
            r[u] = atomicAdd(&lcnt[bin[u]], 1u);
        }
        // phase 2: 4 independent stores (or rare exact-fp32 overflow)
        #pragma unroll
        for (int u = 0; u < 4; ++u) {
            if (r[u] < (unsigned)CAPF) {
                uint2 rec;
                rec.x = ((unsigned)(self[u] & (PSZ_NEW - 1)) << 20) |
                        (unsigned)other[u];
                rec.y = hgb[u];
                bkt[((size_t)blockIdx.x * nbins + bin[u]) * CAPF + r[u]] = rec;
            } else {
                float2 ps = pred[self[u]];
                float2 po = pred[other[u]];
                float t1 = ps.x * po.x + ps.y * po.y;
                float t2 = ps.y * po.x - ps.x * po.y;
                float vs = ps.x * ps.x + ps.y * ps.y;
                float P =  gg[u]  * (vs - t1) - bbv[u] * t2;
                float Q = -bbv[u] * (vs - t1) - gg[u]  * t2;
                unsafeAtomicAdd(&calc[2 * (size_t)self[u]],     P);
                unsafeAtomicAdd(&calc[2 * (size_t)self[u] + 1], Q);
            }
        }
    }
    if ((nE & 1) && tid == 0) {
        int k = nE - 1;
        int a = ei[k], b = ei[nE + k];
        float2 at = ea[k];
        float g = at.x * es0 + em0, bb = at.y * es1 + em1;
        unsigned h = __builtin_bit_cast(unsigned, __floats2half2_rn(g, bb));
        int self[2] = { a, b }, other[2] = { b, a };
        #pragma unroll
        for (int u = 0; u < 2; ++u) {
            int bin = self[u] >> PB_NEW;
            unsigned r = atomicAdd(&lcnt[bin], 1u);
            if (r < (unsigned)CAPF) {
                uint2 rec;
                rec.x = ((unsigned)(self[u] & (PSZ_NEW - 1)) << 20) |
                        (unsigned)other[u];
                rec.y = h;
                bkt[((size_t)blockIdx.x * nbins + bin) * CAPF + r] = rec;
            } else {
                float2 ps = pred[self[u]];
                float2 po = pred[other[u]];
                float P, Q;
                msg_compute(ps, po, at, es0, es1, em0, em1, P, Q);
                unsafeAtomicAdd(&calc[2 * (size_t)self[u]],     P);
                unsafeAtomicAdd(&calc[2 * (size_t)self[u] + 1], Q);
            }
        }
    }

    __syncthreads();
    for (int i = threadIdx.x; i < nbins; i += blockDim.x)
        gcnt[(size_t)blockIdx.x * nbins + i] = min(lcnt[i], (unsigned)CAPF);
}

// Fused gather: software-pipelined pair loop (prefetch next uint4 one iteration
// ahead, unconditional — slot always in-bounds; validity gates only the uses),
// pred[o] fp32 direct; + MSE/PV/phys epilogue.
__global__ __launch_bounds__(K4BLK)
void gather_fused(const uint2*        __restrict__ bkt,
                  const unsigned int* __restrict__ gcnt,
                  const float2* __restrict__ pred,
                  const float*  __restrict__ calc,   // overflow
                  const float4* __restrict__ ty,
                  const float4* __restrict__ mask,
                  const int*    __restrict__ bus,
                  const float*  __restrict__ tvm,
                  const float*  __restrict__ xymean,
                  const float*  __restrict__ xystd,
                  Scalars* sc, int n, int nbins)
{
    __shared__ float accx[PSZ_NEW];
    __shared__ float accy[PSZ_NEW];
    __shared__ float2 plds[PSZ_NEW];
    __shared__ unsigned int cnts[K3GRID];

    int p = blockIdx.x;
    int base = p << PB_NEW;
    for (int i = threadIdx.x; i < PSZ_NEW; i += blockDim.x) {
        accx[i] = 0.0f; accy[i] = 0.0f;
        int g = base + i;
        plds[i] = (g < n) ? pred[g] : make_float2(0.0f, 0.0f);
    }
    for (int b = threadIdx.x; b < K3GRID; b += blockDim.x)
        cnts[b] = gcnt[(size_t)b * nbins + p];
    __syncthreads();

    const int pairs = K3GRID * HALFCAP;
    const uint4* bkt4 = (const uint4*)bkt;

    // software pipeline: rr holds the uint4 for pair index f
    int f = threadIdx.x;
    uint4 rr = make_uint4(0, 0, 0, 0);
    if (f < pairs) {
        int b  = f / HALFCAP;
        int lo = f - b * HALFCAP;
        rr = nt_ld_u4(&bkt4[((size_t)b * nbins + p) * HALFCAP + lo]);
    }
    while (f < pairs) {
        int fn = f + K4BLK;
        uint4 rrn = make_uint4(0, 0, 0, 0);
        if (fn < pairs) {
            int bn  = fn / HALFCAP;
            int lon = fn - bn * HALFCAP;
            rrn = nt_ld_u4(&bkt4[((size_t)bn * nbins + p) * HALFCAP + lon]);
        }
        // process current pair
        int b = f / HALFCAP;
        int t = (f - b * HALFCAP) * 2;
        unsigned c = cnts[b];
        if ((unsigned)t < c) {
            bool v1 = (unsigned)(t + 1) < c;
            int o0   = (int)(rr.x & 0xFFFFFu);
            int lid0 = (int)(rr.x >> 20);
            float2 po0 = pred[o0];
            int lid1 = 0;
            float2 po1 = make_float2(0.0f, 0.0f);
            if (v1) {
                int o1 = (int)(rr.z & 0xFFFFFu);
                lid1 = (int)(rr.z >> 20);
                po1  = pred[o1];
            }
            {
                __half2 h2 = __builtin_bit_cast(__half2, rr.y);
                float g  = __low2float(h2);
                float bb = __high2float(h2);
                float2 ps = plds[lid0];
                float t1 = ps.x * po0.x + ps.y * po0.y;
                float t2 = ps.y * po0.x - ps.x * po0.y;
                float vs = ps.x * ps.x + ps.y * ps.y;
                float P =  g  * (vs - t1) - bb * t2;
                float Q = -bb * (vs - t1) - g  * t2;
                atomicAdd(&accx[lid0], P);
                atomicAdd(&accy[lid0], Q);
            }
            if (v1) {
                __half2 h2 = __builtin_bit_cast(__half2, rr.w);
                float g  = __low2float(h2);
                float bb = __high2float(h2);
                float2 ps = plds[lid1];
                float t1 = ps.x * po1.x + ps.y * po1.y;
                float t2 = ps.y * po1.x - ps.x * po1.y;
                float vs = ps.x * ps.x + ps.y * ps.y;
                float P =  g  * (vs - t1) - bb * t2;
                float Q = -bb * (vs - t1) - g  * t2;
                atomicAdd(&accx[lid1], P);
                atomicAdd(&accy[lid1], Q);
            }
        }
        f = fn;
        rr = rrn;
    }
    __syncthreads();

    // epilogue: MSE + PV + phys for this partition's nodes
    float xs0 = xystd[0] + EPSF, xs1 = xystd[1] + EPSF;
    float xs2 = xystd[2] + EPSF, xs3 = xystd[3] + EPSF;
    float xm0 = xymean[0], xm1 = xymean[1], xm2 = xymean[2], xm3 = xymean[3];

    double mse_num = 0.0, mse_den = 0.0, pv_sum = 0.0, pv_cnt = 0.0, phys = 0.0;
    for (int i = threadIdx.x; i < PSZ_NEW; i += blockDim.x) {
        int g = base + i;
        if (g < n) {
            float2 pp = plds[i];
            float4 t = nt_ld_f4(&ty[g]);
            float4 m = nt_ld_f4(&mask[g]);
            float d0 = pp.x - t.z, d1 = pp.y - t.w;
            mse_num += (double)(d0 * d0 * m.z + d1 * d1 * m.w);
            mse_den += (double)(m.z + m.w);
            float er0 = pp.x * xs2 + xm2;
            float er1 = pp.y * xs3 + xm3;
            float vmsq = er0 * er0 + er1 * er1;
            if (nt_ld_i(&bus[g]) == 1) {
                float tv = nt_ld_f(&tvm[g]);
                pv_sum += (double)fabsf(vmsq - tv * tv);
                pv_cnt += 1.0;
            }
            float2 ov = ((const float2*)calc)[g];
            float vx = t.x * xs0 + xm0 + accx[i] + ov.x;
            float vy = t.y * xs1 + xm1 + accy[i] + ov.y;
            phys += (double)vx * (double)vx + (double)vy * (double)vy;
        }
    }
    mse_num = blockReduceSum(mse_num);
    mse_den = blockReduceSum(mse_den);
    pv_sum  = blockReduceSum(pv_sum);
    pv_cnt  = blockReduceSum(pv_cnt);
    phys    = blockReduceSum(phys);
    if (threadIdx.x == 0) {
        atomicAdd(&sc->mse_num, mse_num);
        atomicAdd(&sc->mse_den, mse_den);
        atomicAdd(&sc->pv_sum,  pv_sum);
        atomicAdd(&sc->pv_cnt,  pv_cnt);
        atomicAdd(&sc->phys_sum, phys);
    }
}

// ---------------- fallback path: direct atomics (exact) ----------------

__global__ void pass2_edges(const int*    __restrict__ ei,
                            const float2* __restrict__ ea,
                            const float2* __restrict__ pred,
                            const float*  __restrict__ emean,
                            const float*  __restrict__ estd,
                            float*        __restrict__ calc,
                            int nE)
{
    float es0 = estd[0] + EPSF, es1 = estd[1] + EPSF;
    float em0 = emean[0], em1 = emean[1];
    int stride = gridDim.x * blockDim.x;
    for (int k = blockIdx.x * blockDim.x + threadIdx.x; k < nE; k += stride) {
        int a = ei[k];
        int b = ei[nE + k];
        float2 at = ea[k];
        float2 pa = pred[a];
        float2 pb = pred[b];
        float Pa, Qa, Pb, Qb;
        msg_compute(pa, pb, at, es0, es1, em0, em1, Pa, Qa);
        msg_compute(pb, pa, at, es0, es1, em0, em1, Pb, Qb);
        unsafeAtomicAdd(&calc[2 * (size_t)a],     Pa);
        unsafeAtomicAdd(&calc[2 * (size_t)a + 1], Qa);
        unsafeAtomicAdd(&calc[2 * (size_t)b],     Pb);
        unsafeAtomicAdd(&calc[2 * (size_t)b + 1], Qb);
    }
}

__global__ void pass3_phys(const float2* __restrict__ calc, Scalars* sc, int n)
{
    double s = 0.0;
    int stride = gridDim.x * blockDim.x;
    for (int i = blockIdx.x * blockDim.x + threadIdx.x; i < n; i += stride) {
        float2 c = calc[i];
        s += (double)c.x * (double)c.x + (double)c.y * (double)c.y;
    }
    s = blockReduceSum(s);
    if (threadIdx.x == 0) atomicAdd(&sc->phys_sum, s);
}

__global__ void finalize_kernel(const Scalars* __restrict__ sc, float* __restrict__ out, int n)
{
    if (threadIdx.x == 0 && blockIdx.x == 0) {
        double mse  = sc->mse_num / (sc->mse_den + 1e-6);
        double phys = sc->phys_sum / (2.0 * (double)n);
        double pv   = (sc->pv_cnt > 0.0) ? (sc->pv_sum / fmax(sc->pv_cnt, 1.0)) : 0.0;
        double total = 0.8 * mse + 0.2 * phys + 0.1 * pv;
        out[0] = (float)total;
        out[1] = (float)mse;
        out[2] = (float)phys;
        out[3] = (float)pv;
    }
}

extern "C" void kernel_launch(void* const* d_in, const int* in_sizes, int n_in,
                              void* d_out, int out_size, void* d_ws, size_t ws_size,
                              hipStream_t stream) {
    const float2* pred   = (const float2*)d_in[0];
    const float4* ty     = (const float4*)d_in[1];
    const float4* mask   = (const float4*)d_in[2];
    const int*    ei     = (const int*)d_in[3];
    const float2* ea     = (const float2*)d_in[4];
    const int*    bus    = (const int*)d_in[5];
    const float*  tvm    = (const float*)d_in[6];
    const float*  xymean = (const float*)d_in[7];
    const float*  xystd  = (const float*)d_in[8];
    const float*  emean  = (const float*)d_in[9];
    const float*  estd   = (const float*)d_in[10];
    float* out = (float*)d_out;

    int n  = in_sizes[0] / 2;   // nodes
    int nE = in_sizes[3] / 2;   // edges

    char* basep = (char*)d_ws;
    Scalars* sc = (Scalars*)basep;
    size_t head = 64;
    float* calc = (float*)(basep + head);
    head += (size_t)2 * n * sizeof(float);
    head = (head + 15) & ~(size_t)15;

    const int BLK = 256, GRID = 2048;

    // ---- fast tier: PB=11, 8B records, cap=CAPF, block-major buckets ----
    int nbinsN = (n + PSZ_NEW - 1) >> PB_NEW;
    size_t slotsN = (size_t)K3GRID * nbinsN;
    size_t offN = head + slotsN * sizeof(unsigned int);
    offN = (offN + 15) & ~(size_t)15;
    size_t needN = offN + slotsN * (size_t)CAPF * sizeof(uint2);
    bool useNew = (n <= (1 << 20)) && (nbinsN <= MAXBINS) && (needN <= ws_size);

    if (useNew) {
        unsigned int* gcnt = (unsigned int*)(basep + head);
        uint2* bkt = (uint2*)(basep + offN);

        zero_ws_kernel<<<1024, 256, 0, stream>>>(calc, (double*)sc, 2 * n);
        scatter_h2<<<K3GRID, K3BLK, 0, stream>>>(ei, ea, pred, emean, estd,
                                                 bkt, gcnt, calc, nE, nbinsN);
        gather_fused<<<nbinsN, K4BLK, 0, stream>>>(bkt, gcnt, pred, calc, ty, mask,
                                                   bus, tvm, xymean, xystd, sc, n, nbinsN);
        finalize_kernel<<<1, 64, 0, stream>>>(sc, out, n);
        return;
    }

    // ---- fallback: direct atomics (exact) ----
    zero_ws_kernel<<<1024, 256, 0, stream>>>(calc, (double*)sc, 0);
    pass1_nodes<<<GRID, BLK, 0, stream>>>(pred, ty, mask, bus, tvm, xymean, xystd,
                                          (float2*)calc, sc, n, /*seed=*/1);
    pass2_edges<<<GRID, BLK, 0, stream>>>(ei, ea, pred, emean, estd, calc, nE);
    pass3_phys<<<GRID, BLK, 0, stream>>>((const float2*)calc, sc, n);
    finalize_kernel<<<1, 64, 0, stream>>>(sc, out, n);
}